// Round 1
// baseline (150.774 us; speedup 1.0000x reference)
//
#include <hip/hip_runtime.h>
#include <hip/hip_bf16.h>

// Problem constants
#define NROWS 512          // N
#define FEAT  8192         // NUM_CHANNELS*4*4
#define BDIM  64
#define CDIM  16
#define MCOLS 1024         // BDIM*CDIM
#define OUTC  8256         // FEAT + BDIM
#define KSPLIT 4
#define KCHUNK (FEAT / KSPLIT)   // 2048

typedef __bf16 bf16x8 __attribute__((ext_vector_type(8)));
typedef float  floatx4 __attribute__((ext_vector_type(4)));

static __device__ inline unsigned short f2bf(float f) {
    unsigned int x = __builtin_bit_cast(unsigned int, f);
    unsigned int r = (x + 0x7FFFu + ((x >> 16) & 1u)) >> 16;   // RNE
    return (unsigned short)r;
}

// ---------------------------------------------------------------------------
// Kernel 1: x fp32 -> bf16 (for GEMM), and copy x into out[:, 0:8192]
// grid: 512*8192/4 / 256 = 4096 blocks
// ---------------------------------------------------------------------------
__global__ __launch_bounds__(256) void convx_kernel(const float* __restrict__ x,
                                                    unsigned short* __restrict__ xb,
                                                    float* __restrict__ out) {
    int gid = blockIdx.x * 256 + threadIdx.x;      // float4 index, 0..1048575
    float4 v = *(const float4*)(x + (size_t)gid * 4);
    ushort4 u;
    u.x = f2bf(v.x); u.y = f2bf(v.y); u.z = f2bf(v.z); u.w = f2bf(v.w);
    *(ushort4*)(xb + (size_t)gid * 4) = u;
    int row  = gid >> 11;            // 2048 float4 per row
    int col4 = gid & 2047;
    *(float4*)(out + (size_t)row * OUTC + col4 * 4) = v;
}

// ---------------------------------------------------------------------------
// Kernel 2: T (8192x1024 fp32, row-major) -> Tt (1024x8192 bf16, row-major)
// 32x32 tiles through LDS. grid = (8192/32)*(1024/32) = 8192 blocks, 256 thr.
// ---------------------------------------------------------------------------
__global__ __launch_bounds__(256) void convt_kernel(const float* __restrict__ T,
                                                    unsigned short* __restrict__ Tt) {
    int bid = blockIdx.x;
    int kt = bid & 255;              // 256 k-tiles
    int nt = bid >> 8;               // 32 n-tiles
    __shared__ float lds[32][33];
    int tx = threadIdx.x & 31;
    int ty = threadIdx.x >> 5;       // 0..7
#pragma unroll
    for (int p = 0; p < 4; ++p) {
        int kk = ty + p * 8;
        lds[kk][tx] = T[(size_t)(kt * 32 + kk) * MCOLS + nt * 32 + tx];
    }
    __syncthreads();
#pragma unroll
    for (int p = 0; p < 4; ++p) {
        int nn = ty + p * 8;
        Tt[(size_t)(nt * 32 + nn) * FEAT + kt * 32 + tx] = f2bf(lds[tx][nn]);
    }
}

// ---------------------------------------------------------------------------
// Kernel 3: M = x @ T via bf16 MFMA 16x16x32, split-K=4 partials (no atomics).
// Block: 256 thr = 4 waves, 64x64 output tile, BK=32.
// grid = 8(m) * 16(n) * 4(ksplit) = 512 blocks.
// A frag: lane l holds A[m=l&15][k=(l>>4)*8 + j]; B frag: B[k][n=l&15] same k.
// D: col = l&15, row = (l>>4)*4 + r.
// ---------------------------------------------------------------------------
__global__ __launch_bounds__(256) void gemm_kernel(const unsigned short* __restrict__ xb,
                                                   const unsigned short* __restrict__ Tt,
                                                   float* __restrict__ Mp) {
    int bid = blockIdx.x;
    int mt = bid & 7;
    int nt = (bid >> 3) & 15;
    int ks = bid >> 7;
    int m0 = mt * 64, n0 = nt * 64, kbase = ks * KCHUNK;

    __shared__ __align__(16) unsigned short ldsA[64][40];   // pad: 80B row stride
    __shared__ __align__(16) unsigned short ldsB[64][40];

    int t = threadIdx.x;
    int lrow = t >> 2;               // 0..63
    int lc8  = t & 3;                // 0..3 -> 8 bf16 (16B) chunks
    const unsigned short* gA = xb + (size_t)(m0 + lrow) * FEAT + kbase + lc8 * 8;
    const unsigned short* gB = Tt + (size_t)(n0 + lrow) * FEAT + kbase + lc8 * 8;

    int lane = t & 63, w = t >> 6;
    int fm = lane & 15, fq = lane >> 4;
    const unsigned short* pA  = &ldsA[w * 16 + fm][fq * 8];
    const unsigned short* pB0 = &ldsB[ 0 + fm][fq * 8];
    const unsigned short* pB1 = &ldsB[16 + fm][fq * 8];
    const unsigned short* pB2 = &ldsB[32 + fm][fq * 8];
    const unsigned short* pB3 = &ldsB[48 + fm][fq * 8];

    floatx4 acc0 = {}, acc1 = {}, acc2 = {}, acc3 = {};

    for (int kk = 0; kk < KCHUNK; kk += 32) {
        uint4 a = *(const uint4*)(gA + kk);
        uint4 b = *(const uint4*)(gB + kk);
        __syncthreads();
        *(uint4*)&ldsA[lrow][lc8 * 8] = a;
        *(uint4*)&ldsB[lrow][lc8 * 8] = b;
        __syncthreads();
        bf16x8 af = *(const bf16x8*)pA;
        acc0 = __builtin_amdgcn_mfma_f32_16x16x32_bf16(af, *(const bf16x8*)pB0, acc0, 0, 0, 0);
        acc1 = __builtin_amdgcn_mfma_f32_16x16x32_bf16(af, *(const bf16x8*)pB1, acc1, 0, 0, 0);
        acc2 = __builtin_amdgcn_mfma_f32_16x16x32_bf16(af, *(const bf16x8*)pB2, acc2, 0, 0, 0);
        acc3 = __builtin_amdgcn_mfma_f32_16x16x32_bf16(af, *(const bf16x8*)pB3, acc3, 0, 0, 0);
    }

    float* outp = Mp + (size_t)ks * NROWS * MCOLS;
    int row = m0 + w * 16 + fq * 4;
    int col = n0 + fm;
#pragma unroll
    for (int r = 0; r < 4; ++r) {
        outp[(size_t)(row + r) * MCOLS + col +  0] = acc0[r];
        outp[(size_t)(row + r) * MCOLS + col + 16] = acc1[r];
        outp[(size_t)(row + r) * MCOLS + col + 32] = acc2[r];
        outp[(size_t)(row + r) * MCOLS + col + 48] = acc3[r];
    }
}

// ---------------------------------------------------------------------------
// Kernel 4: o[i,b] = sum_j exp(-sum_c |M[i,b,c]-M[j,b,c]|), written to
// out[:, 8192:8256]. Sums the 4 split-K partials during LDS staging.
// grid = 8 i-tiles * 64 b = 512 blocks, 256 thr = 4 waves.
// Wave w handles j in [w*128, w*128+128) for all 64 lanes (lane = i offset);
// j is wave-uniform -> LDS broadcast reads.
// ---------------------------------------------------------------------------
__global__ __launch_bounds__(256) void pairwise_kernel(const float* __restrict__ Mp,
                                                       float* __restrict__ out) {
    int b  = blockIdx.x & 63;
    int it = blockIdx.x >> 6;        // 0..7
    __shared__ __align__(16) float ldsM[NROWS][CDIM];   // 32 KB
    __shared__ float partial[4][64];

    int t = threadIdx.x;
#pragma unroll
    for (int p = 0; p < 8; ++p) {
        int idx = t + p * 256;       // float4 index, 2048 total
        int j = idx >> 2, c4 = idx & 3;
        const float* base = Mp + (size_t)j * MCOLS + b * CDIM + c4 * 4;
        float4 v0 = *(const float4*)(base);
        float4 v1 = *(const float4*)(base + 1 * NROWS * MCOLS);
        float4 v2 = *(const float4*)(base + 2 * NROWS * MCOLS);
        float4 v3 = *(const float4*)(base + 3 * NROWS * MCOLS);
        float4 s;
        s.x = v0.x + v1.x + v2.x + v3.x;
        s.y = v0.y + v1.y + v2.y + v3.y;
        s.z = v0.z + v1.z + v2.z + v3.z;
        s.w = v0.w + v1.w + v2.w + v3.w;
        *(float4*)&ldsM[j][c4 * 4] = s;
    }
    __syncthreads();

    int lane = t & 63, w = t >> 6;
    int i = it * 64 + lane;
    float mi[CDIM];
#pragma unroll
    for (int c = 0; c < CDIM; ++c) mi[c] = ldsM[i][c];

    float acc = 0.0f;
    int j0 = w * 128;
    for (int jj = j0; jj < j0 + 128; ++jj) {
        float d = 0.0f;
#pragma unroll
        for (int c = 0; c < CDIM; ++c) d += fabsf(mi[c] - ldsM[jj][c]);
        acc += __expf(-d);
    }
    partial[w][lane] = acc;
    __syncthreads();
    if (w == 0) {
        float o = partial[0][lane] + partial[1][lane] + partial[2][lane] + partial[3][lane];
        out[(size_t)i * OUTC + FEAT + b] = o;
    }
}

// ---------------------------------------------------------------------------
extern "C" void kernel_launch(void* const* d_in, const int* in_sizes, int n_in,
                              void* d_out, int out_size, void* d_ws, size_t ws_size,
                              hipStream_t stream) {
    const float* x = (const float*)d_in[0];   // (512, 512, 4, 4) = (512, 8192)
    const float* T = (const float*)d_in[1];   // (8192, 1024)
    float* out = (float*)d_out;               // (512, 8256)

    // workspace layout: xb 8MB | Tt 16MB | Mp 4x2MB = 8MB  (total 32MB)
    unsigned short* xb = (unsigned short*)d_ws;
    unsigned short* Tt = (unsigned short*)((char*)d_ws + (8u << 20));
    float*          Mp = (float*)((char*)d_ws + (24u << 20));

    convx_kernel<<<4096, 256, 0, stream>>>(x, xb, out);
    convt_kernel<<<8192, 256, 0, stream>>>(T, Tt);
    gemm_kernel<<<512, 256, 0, stream>>>(xb, Tt, Mp);
    pairwise_kernel<<<512, 256, 0, stream>>>(Mp, out);
}

// Round 2
// 137.134 us; speedup vs baseline: 1.0995x; 1.0995x over previous
//
#include <hip/hip_runtime.h>

// Problem constants
#define NROWS 512          // N
#define FEAT  8192         // NUM_CHANNELS*4*4
#define BDIM  64
#define CDIM  16
#define MCOLS 1024         // BDIM*CDIM
#define OUTC  8256         // FEAT + BDIM
#define KSPLIT 16
#define KCHUNK (FEAT / KSPLIT)     // 512
#define MSIZE  (NROWS * MCOLS)     // 524288 floats = 2 MB

typedef __bf16 bf16x8 __attribute__((ext_vector_type(8)));
typedef float  floatx4 __attribute__((ext_vector_type(4)));

#define AS1 __attribute__((address_space(1)))
#define AS3 __attribute__((address_space(3)))

// async global->LDS, 16B per lane. LDS dest = wave-uniform base + lane*16.
static __device__ __forceinline__ void gload16(const void* g, void* l) {
    __builtin_amdgcn_global_load_lds((AS1 void*)(g), (AS3 void*)(l), 16, 0, 0);
}

static __device__ __forceinline__ unsigned short f2bf(float f) {
    unsigned int x = __builtin_bit_cast(unsigned int, f);
    unsigned int r = (x + 0x7FFFu + ((x >> 16) & 1u)) >> 16;   // RNE
    return (unsigned short)r;
}

// ---------------------------------------------------------------------------
// prep: blocks [0,4096): x fp32 -> bf16 xb + copy x into out[:, :8192]
//       blocks [4096,6144): T (8192x1024 f32) -> Tt (1024x8192 bf16), 64x64
//       tiles via LDS, 32B/lane vectorized output stores.
// ---------------------------------------------------------------------------
__global__ __launch_bounds__(256) void prep_kernel(const float* __restrict__ x,
                                                   const float* __restrict__ T,
                                                   unsigned short* __restrict__ xb,
                                                   unsigned short* __restrict__ Tt,
                                                   float* __restrict__ out) {
    __shared__ float lds[64][65];     // +1 pad: 2-way bank aliasing only (free)
    int bid = blockIdx.x, t = threadIdx.x;
    if (bid < 4096) {
        int gid = bid * 256 + t;                 // float4 index
        float4 v = *(const float4*)(x + (size_t)gid * 4);
        ushort4 u;
        u.x = f2bf(v.x); u.y = f2bf(v.y); u.z = f2bf(v.z); u.w = f2bf(v.w);
        *(ushort4*)(xb + (size_t)gid * 4) = u;
        int row = gid >> 11, col4 = gid & 2047;
        *(float4*)(out + (size_t)row * OUTC + col4 * 4) = v;
    } else {
        int b2 = bid - 4096;
        int kt = b2 & 127, nt = b2 >> 7;         // 128 k-tiles x 16 n-tiles
        int kk = t >> 2, q = t & 3;
#pragma unroll
        for (int p = 0; p < 4; ++p) {
            int c4 = q + p * 4;                  // 16 float4 per 64-wide row
            float4 v = *(const float4*)(T + (size_t)(kt * 64 + kk) * MCOLS + nt * 64 + c4 * 4);
            lds[kk][c4 * 4 + 0] = v.x; lds[kk][c4 * 4 + 1] = v.y;
            lds[kk][c4 * 4 + 2] = v.z; lds[kk][c4 * 4 + 3] = v.w;
        }
        __syncthreads();
        int nr = t >> 2, ck = t & 3;             // out row n, 16-k chunk
        unsigned int w[8];
#pragma unroll
        for (int j = 0; j < 8; ++j) {
            unsigned int lo = f2bf(lds[ck * 16 + j * 2 + 0][nr]);
            unsigned int hi = f2bf(lds[ck * 16 + j * 2 + 1][nr]);
            w[j] = lo | (hi << 16);
        }
        uint4* dst = (uint4*)(Tt + (size_t)(nt * 64 + nr) * FEAT + kt * 64 + ck * 16);
        dst[0] = make_uint4(w[0], w[1], w[2], w[3]);
        dst[1] = make_uint4(w[4], w[5], w[6], w[7]);
    }
}

// ---------------------------------------------------------------------------
// gemm: M = x @ T, bf16 MFMA 16x16x32, m97-style 128x128 tile, BK=32,
// global_load_lds width-16 staging with XOR-swizzled source chunks so the
// forced (base + lane*16) LDS layout reads back conflict-free as b128 frags.
// grid = 4(mt) x 8(nt) x 16(ksplit) = 512 blocks, 256 thr = 4 waves (2x2).
// ---------------------------------------------------------------------------
__global__ __launch_bounds__(256, 2) void gemm_kernel(const unsigned short* __restrict__ xb,
                                                      const unsigned short* __restrict__ Tt,
                                                      float* __restrict__ Mp) {
    __shared__ __align__(16) unsigned short ldsA[128 * 32];   // 8 KB, 64B/row
    __shared__ __align__(16) unsigned short ldsB[128 * 32];

    int bid = blockIdx.x;
    int mt = bid & 3, nt = (bid >> 2) & 7, ks = bid >> 5;
    int m0 = mt * 128, n0 = nt * 128, kbase = ks * KCHUNK;
    int t = threadIdx.x, w = t >> 6, l = t & 63;

    // staging: wave w covers rows [w*32, w*32+32) in two 16-row instructions.
    // lane l -> row r0 = w*32 + (l>>2), slot s = l&3, fetches global chunk
    // c = s ^ ((r>>1)&3)  (same swizzle for r and r+16 since 16>>1 & 3 == 0).
    int r0 = w * 32 + (l >> 2);
    int c  = (l & 3) ^ ((r0 >> 1) & 3);
    const unsigned short* gA0 = xb + (size_t)(m0 + r0) * FEAT + kbase + c * 8;
    const unsigned short* gB0 = Tt + (size_t)(n0 + r0) * FEAT + kbase + c * 8;
    unsigned short* lA0 = &ldsA[w * 1024];
    unsigned short* lA1 = &ldsA[w * 1024 + 512];
    unsigned short* lB0 = &ldsB[w * 1024];
    unsigned short* lB1 = &ldsB[w * 1024 + 512];

    // fragment read pointers (swizzle-aware)
    int wr = w >> 1, wc = w & 1, fm = l & 15, fq = l >> 4;
    int swz = (fm >> 1) & 3;
    const unsigned short* pa[4];
    const unsigned short* pb[4];
#pragma unroll
    for (int a = 0; a < 4; ++a)
        pa[a] = &ldsA[(wr * 64 + a * 16 + fm) * 32 + ((fq ^ swz) * 8)];
#pragma unroll
    for (int b = 0; b < 4; ++b)
        pb[b] = &ldsB[(wc * 64 + b * 16 + fm) * 32 + ((fq ^ swz) * 8)];

    floatx4 acc[4][4] = {};

    for (int kk = 0; kk < KCHUNK; kk += 32) {
        if (kk) __syncthreads();                 // protect LDS from overwrite
        gload16(gA0 + kk,             lA0);
        gload16(gA0 + 16 * FEAT + kk, lA1);
        gload16(gB0 + kk,             lB0);
        gload16(gB0 + 16 * FEAT + kk, lB1);
        __syncthreads();                         // drains vmcnt -> LDS visible
        bf16x8 af[4], bfr[4];
#pragma unroll
        for (int a = 0; a < 4; ++a) af[a] = *(const bf16x8*)pa[a];
#pragma unroll
        for (int b = 0; b < 4; ++b) bfr[b] = *(const bf16x8*)pb[b];
#pragma unroll
        for (int a = 0; a < 4; ++a)
#pragma unroll
            for (int b = 0; b < 4; ++b)
                acc[a][b] = __builtin_amdgcn_mfma_f32_16x16x32_bf16(af[a], bfr[b], acc[a][b], 0, 0, 0);
    }

    // epilogue: D layout col = l&15, row = (l>>4)*4 + r
    float* outp = Mp + (size_t)ks * MSIZE;
    int gr0 = m0 + wr * 64, gc0 = n0 + wc * 64;
#pragma unroll
    for (int a = 0; a < 4; ++a)
#pragma unroll
        for (int r = 0; r < 4; ++r) {
            int row = gr0 + a * 16 + fq * 4 + r;
#pragma unroll
            for (int b = 0; b < 4; ++b)
                outp[(size_t)row * MCOLS + gc0 + b * 16 + fm] = acc[a][b][r];
        }
}

// ---------------------------------------------------------------------------
// reduce: Msum = sum of 16 split-K partials. 512 blocks x 256 thr, float4.
// ---------------------------------------------------------------------------
__global__ __launch_bounds__(256) void reduce_kernel(const float* __restrict__ Mp,
                                                     float* __restrict__ Ms) {
    int gid = blockIdx.x * 256 + threadIdx.x;    // float4 index, 0..131071
    const float4* p = (const float4*)Mp;
    float4 s = p[gid];
#pragma unroll
    for (int k = 1; k < KSPLIT; ++k) {
        float4 v = p[(size_t)k * (MSIZE / 4) + gid];
        s.x += v.x; s.y += v.y; s.z += v.z; s.w += v.w;
    }
    ((float4*)Ms)[gid] = s;
}

// ---------------------------------------------------------------------------
// pairwise: o[i,b] = sum_j exp(-sum_c |M[i,b,c]-M[j,b,c]|) -> out[:,8192:].
// grid = 8 i-tiles x 64 b = 512 blocks, 256 thr = 4 waves. Wave w does j in
// [w*128, w*128+128); j wave-uniform -> LDS broadcast. Row pad 20 floats.
// ---------------------------------------------------------------------------
__global__ __launch_bounds__(256) void pairwise_kernel(const float* __restrict__ Ms,
                                                       float* __restrict__ out) {
    __shared__ float ldsM[NROWS * 20];           // 40 KB, padded rows
    __shared__ float partial[4][64];
    int b = blockIdx.x & 63, it = blockIdx.x >> 6;
    int t = threadIdx.x;
#pragma unroll
    for (int p = 0; p < 8; ++p) {
        int idx = t + p * 256;                   // 2048 float4 total
        int j = idx >> 2, c4 = idx & 3;
        float4 v = *(const float4*)(Ms + (size_t)j * MCOLS + b * CDIM + c4 * 4);
        *(float4*)&ldsM[j * 20 + c4 * 4] = v;
    }
    __syncthreads();

    int lane = t & 63, w = t >> 6;
    int i = it * 64 + lane;
    float mi[CDIM];
#pragma unroll
    for (int cc = 0; cc < CDIM; ++cc) mi[cc] = ldsM[i * 20 + cc];

    float acc = 0.0f;
    for (int jj = w * 128; jj < w * 128 + 128; ++jj) {
        float d = 0.0f;
#pragma unroll
        for (int cc = 0; cc < CDIM; ++cc) d += fabsf(mi[cc] - ldsM[jj * 20 + cc]);
        acc += __expf(-d);
    }
    partial[w][lane] = acc;
    __syncthreads();
    if (w == 0) {
        float o = partial[0][lane] + partial[1][lane] + partial[2][lane] + partial[3][lane];
        out[(size_t)i * OUTC + FEAT + b] = o;
    }
}

// ---------------------------------------------------------------------------
extern "C" void kernel_launch(void* const* d_in, const int* in_sizes, int n_in,
                              void* d_out, int out_size, void* d_ws, size_t ws_size,
                              hipStream_t stream) {
    const float* x = (const float*)d_in[0];      // (512, 8192)
    const float* T = (const float*)d_in[1];      // (8192, 1024)
    float* out = (float*)d_out;                  // (512, 8256)

    // ws layout: xb 8MB | Tt 16MB | Mp 16x2MB=32MB | Msum 2MB  (58MB total)
    unsigned short* xb = (unsigned short*)d_ws;
    unsigned short* Tt = (unsigned short*)((char*)d_ws + (8u << 20));
    float*          Mp = (float*)((char*)d_ws + (24u << 20));
    float*          Ms = (float*)((char*)d_ws + (56u << 20));

    prep_kernel<<<6144, 256, 0, stream>>>(x, T, xb, Tt, out);
    gemm_kernel<<<512, 256, 0, stream>>>(xb, Tt, Mp);
    reduce_kernel<<<512, 256, 0, stream>>>(Mp, Ms);
    pairwise_kernel<<<512, 256, 0, stream>>>(Ms, out);
}